// Round 16
// baseline (2405.428 us; speedup 1.0000x reference)
//
#include <hip/hip_runtime.h>
#include <hip/hip_bf16.h>

#define N_LAYERS 1000
#define DD 100
#define DOUT 10
#define TM 64
#define ROWB 264                  // act row stride bytes: 66 words = 2 mod 32 -> 2-way banks (free)
#define PLANE (TM * ROWB)         // 16896 B = one act buffer (single bf16 plane)
#define SMEM_BYTES (2 * PLANE)    // double-buffered: 33792 B -> 4 wgs/CU
#define ROW32 (32 * ROWB)         // 8448: +1 m-tile offset, compile-time immediate
#define LCHUNK 14336              // packed W bytes per (layer, group)
#define LSTRIDE (2 * LCHUNK)      // 28672 B per layer

typedef short s4v __attribute__((ext_vector_type(4)));
typedef short s8v __attribute__((ext_vector_type(8)));
typedef float f16v __attribute__((ext_vector_type(16)));

__device__ __forceinline__ unsigned short f2bf(float f) {
  __hip_bfloat16 h = __float2bfloat16(f);   // HW RNE
  return *reinterpret_cast<unsigned short*>(&h);
}
__device__ __forceinline__ float bf2f(unsigned short h) {
  return __uint_as_float(((unsigned)h) << 16);
}

// ---------------- prologue: W (f32) + bias -> lane-packed bf16 fragments (hi only) ----------
// byte off = (L*2+g)*LCHUNK + ks*2048 + f*1024 + lane*16
// frag: n = g*64+f*32+(lane&31), k = ks*16+(lane>>5)*8+j ; k==100 holds bias; pads zero.
__global__ __launch_bounds__(256)
void presplit_kernel(const float* __restrict__ W, const float* __restrict__ b,
                     char* __restrict__ hi_g) {
  int idx = blockIdx.x * 256 + threadIdx.x;
  if (idx >= N_LAYERS * 2 * 7 * 2 * 64) return;
  int lane = idx & 63;
  int f = (idx >> 6) & 1;
  int r = idx >> 7;
  int ks = r % 7;
  int q = r / 7;
  int g = q & 1;
  int L = q >> 1;
  int n = g * 64 + f * 32 + (lane & 31);
  int k0 = ks * 16 + (lane >> 5) * 8;
  s8v hv;
#pragma unroll
  for (int j = 0; j < 8; ++j) {
    int k = k0 + j;
    float v = 0.0f;
    if (n < DD) {
      if (k < DD) v = W[((size_t)L * DD + n) * DD + k];
      else if (k == DD) v = b[(size_t)L * DD + n];
    }
    hv[j] = (short)f2bf(v);
  }
  *(s8v*)(hi_g + (size_t)idx * 16) = hv;
}

// fallback W gather from raw f32 (both f-halves of group g; used when d_ws too small)
__device__ __forceinline__ void wload_f32(s8v* h, int L, int ks, int g,
                                          int l31, int lhi,
                                          const float* __restrict__ W_g,
                                          const float* __restrict__ b_g) {
  int k0 = ks * 16 + lhi * 8;
#pragma unroll
  for (int f = 0; f < 2; ++f) {
    int n = g * 64 + f * 32 + l31;
    s8v hv;
#pragma unroll
    for (int j = 0; j < 8; ++j) {
      int k = k0 + j;
      float v = 0.0f;
      if (n < DD) {
        if (k < DD) v = W_g[((size_t)L * DD + n) * DD + k];
        else if (k == DD) v = b_g[(size_t)L * DD + n];
      }
      hv[j] = (short)f2bf(v);
    }
    h[f] = hv;
  }
}

// ---------------- one layer: wave = 1 m-tile x 2 n-tiles (64 ch), depth-2 W slots ----------
// Act read (2x b64) amortizes over 2 MFMAs; 14 MFMA/wave/layer.
template <int PRE>
__device__ __forceinline__ void do_layer(
    int L, const char* __restrict__ rb, char* __restrict__ wb,
    int g, int l31, int lhi,
    const char* __restrict__ pH, int woff,
    s8v (&wh)[2][2], f16v (&xr)[2],
    const float* __restrict__ W_g, const float* __restrict__ b_g) {
  f16v acc[2];
#pragma unroll
  for (int f = 0; f < 2; ++f)
#pragma unroll
    for (int r = 0; r < 16; ++r) acc[f][r] = 0.0f;

#pragma unroll
  for (int ks = 0; ks < 7; ++ks) {
    const int s = ks & 1;
    s4v a0 = *(const s4v*)(rb + ks * 32);
    s4v a1 = *(const s4v*)(rb + ks * 32 + 8);
    s8v ah = __builtin_shufflevector(a0, a1, 0, 1, 2, 3, 4, 5, 6, 7);
    acc[0] = __builtin_amdgcn_mfma_f32_32x32x16_bf16(wh[s][0], ah, acc[0], 0, 0, 0);
    acc[1] = __builtin_amdgcn_mfma_f32_32x32x16_bf16(wh[s][1], ah, acc[1], 0, 0, 0);

    // depth-2 prefetch; cross-layer refill at ks==6 (r12-proven schedule)
    if (ks < 5) {
      if (PRE) {
        const char* p = pH + woff + (ks + 2) * 2048;
        wh[s][0] = *(const s8v*)(p);
        wh[s][1] = *(const s8v*)(p + 1024);
      } else {
        wload_f32(wh[s], L, ks + 2, g, l31, lhi, W_g, b_g);
      }
    } else if (ks == 6 && L + 1 < N_LAYERS) {
      if (PRE) {
        const char* p = pH + woff + LSTRIDE;
        wh[0][0] = *(const s8v*)(p);
        wh[0][1] = *(const s8v*)(p + 1024);
        wh[1][0] = *(const s8v*)(p + 2048);
        wh[1][1] = *(const s8v*)(p + 3072);
      } else {
        wload_f32(wh[0], L + 1, 0, g, l31, lhi, W_g, b_g);
        wload_f32(wh[1], L + 1, 1, g, l31, lhi, W_g, b_g);
      }
    }
  }

  // ---- epilogue: relu (+residual at block end), cast bf16, write this m-tile ----
  const bool bend = ((L % 10) == 9);
#pragma unroll
  for (int f = 0; f < 2; ++f) {
#pragma unroll
    for (int q = 0; q < 4; ++q) {
      const int n0 = g * 64 + f * 32 + 8 * q + 4 * lhi;
      char* dst = wb + f * 64 + q * 16;
      if (n0 == 100) {   // bias column: act[100]=1.0, pads 101..103 = 0
        s4v hq;
        hq[0] = (short)0x3F80; hq[1] = 0; hq[2] = 0; hq[3] = 0;
        *(s4v*)dst = hq;
      } else {
        s4v hq;
#pragma unroll
        for (int j = 0; j < 4; ++j) {
          const int r = q * 4 + j;
          float o = fmaxf(acc[f][r], 0.0f);
          if (bend) { o += xr[f][r]; xr[f][r] = o; }   // exact f32 stream carrier
          hq[j] = (short)f2bf(o);
        }
        *(s4v*)dst = hq;
      }
    }
  }
  __syncthreads();   // single barrier per layer (double buffer)
}

// ---------------- main kernel: 1024 wgs x 256 thr, 4 wgs/CU = 16 waves/CU (4/SIMD) --------
// wg = 64 batch rows, 4 waves. Wave wv = (mi, gi): mi = wv&1 m-tile (rows mi*32..+32),
// gi = wv>>1 channel group [gi*64, gi*64+64). Act reads: own m-tile only (112 KB/CU/layer);
// W: wave-pairs load identical fragments back-to-back -> L1 dedup.
// Register budget (64 arch / 64 acc rigid split at 4 waves/SIMD):
// acc-side = acc(32)+xr(32) = 64 exactly; arch-side = wh(16)+ah(4)+temps ~45 < 64.
template <int PRE>
__global__ __launch_bounds__(256, 4)
void resnet_main(const float* __restrict__ x_g,
                 const float* __restrict__ W_g, const float* __restrict__ b_g,
                 const float* __restrict__ Wf_g, const float* __restrict__ bf_g,
                 float* __restrict__ out_g,
                 const char* __restrict__ whi_g) {
  extern __shared__ char smem[];

  const int tid = threadIdx.x;
  const int lane = tid & 63;
  const int wv = tid >> 6;         // wave 0..3
  const int mi = wv & 1;           // m-tile
  const int g = wv >> 1;           // channel group (full LCHUNK group)
  const int l31 = lane & 31;
  const int lhi = lane >> 5;
  const size_t mbase = (size_t)blockIdx.x * TM;

  // ---- initial activation staging into buf A: bf16(x); k==100 -> 1.0; k>100 -> 0 ----
  for (int idx = tid; idx < TM * 16; idx += 256) {
    int m = idx >> 4, kb = idx & 15;
    s4v h0, h1;
#pragma unroll
    for (int j = 0; j < 8; ++j) {
      int k = kb * 8 + j;
      float v = (k < DD) ? x_g[(mbase + m) * DD + k] : (k == DD ? 1.0f : 0.0f);
      if (j < 4) h0[j] = (short)f2bf(v);
      else       h1[j - 4] = (short)f2bf(v);
    }
    char* p = smem + m * ROWB + kb * 16;
    *(s4v*)p = h0;
    *(s4v*)(p + 8) = h1;
  }

  // ---- residual: block input in f32 registers, C-fragment layout (2 n-tiles, 1 m-tile) ----
  f16v xr[2];
#pragma unroll
  for (int f = 0; f < 2; ++f)
#pragma unroll
    for (int r = 0; r < 16; ++r) {
      int n = g * 64 + f * 32 + (r & 3) + 8 * (r >> 2) + 4 * lhi;
      xr[f][r] = (n < DD) ? x_g[(mbase + mi * 32 + l31) * DD + n] : 0.0f;
    }

  // ---- depth-2 W register pipeline: preload ks=0,1 of layer 0 (group g, both f-halves) ----
  const char* pH = whi_g + (size_t)g * LCHUNK + lane * 16;
  s8v wh[2][2];
  if (PRE) {
    wh[0][0] = *(const s8v*)(pH);
    wh[0][1] = *(const s8v*)(pH + 1024);
    wh[1][0] = *(const s8v*)(pH + 2048);
    wh[1][1] = *(const s8v*)(pH + 3072);
  } else {
    wload_f32(wh[0], 0, 0, g, l31, lhi, W_g, b_g);
    wload_f32(wh[1], 0, 1, g, l31, lhi, W_g, b_g);
  }

  __syncthreads();

  // buffer A = smem, buffer B = smem + PLANE; layer L reads buf[L&1], writes buf[~L&1]
  const char* rbA = smem + l31 * ROWB + mi * ROW32 + lhi * 16;
  const char* rbB = rbA + PLANE;
  char* wbA = smem + l31 * ROWB + mi * ROW32 + g * 128 + lhi * 8;
  char* wbB = wbA + PLANE;

  int woff = 0;
  for (int L = 0; L < N_LAYERS; L += 2) {
    do_layer<PRE>(L,     rbA, wbB, g, l31, lhi, pH, woff,           wh, xr, W_g, b_g);
    do_layer<PRE>(L + 1, rbB, wbA, g, l31, lhi, pH, woff + LSTRIDE, wh, xr, W_g, b_g);
    woff += 2 * LSTRIDE;
  }

  // ---- final projection: out = act @ Wf^T + bf  (act = buf A after layer 999) ----
  if (tid < TM) {
    int m = tid;
    const char* p = smem + m * ROWB;
    float xv[104];
#pragma unroll
    for (int kb = 0; kb < 13; ++kb) {
      s4v h0 = *(const s4v*)(p + kb * 16);
      s4v h1 = *(const s4v*)(p + kb * 16 + 8);
#pragma unroll
      for (int j = 0; j < 4; ++j) {
        xv[kb * 8 + j]     = bf2f((unsigned short)h0[j]);
        xv[kb * 8 + 4 + j] = bf2f((unsigned short)h1[j]);
      }
    }
#pragma unroll
    for (int o = 0; o < DOUT; ++o) {
      float s = bf_g[o];
#pragma unroll
      for (int k = 0; k < DD; ++k) s += xv[k] * Wf_g[o * DD + k];
      out_g[(mbase + m) * DOUT + o] = s;
    }
  }
}

extern "C" void kernel_launch(void* const* d_in, const int* in_sizes, int n_in,
                              void* d_out, int out_size, void* d_ws, size_t ws_size,
                              hipStream_t stream) {
  const float* x = (const float*)d_in[0];
  const float* W = (const float*)d_in[1];
  const float* b = (const float*)d_in[2];
  const float* Wf = (const float*)d_in[3];
  const float* bf = (const float*)d_in[4];
  float* out = (float*)d_out;

  const size_t need = (size_t)N_LAYERS * 2 * LCHUNK;          // 28.672 MB (hi only)
  const int nwg = 65536 / TM;                                 // 1024
  if (ws_size >= need) {
    char* whi = (char*)d_ws;
    const int chunks = N_LAYERS * 2 * 7 * 2 * 64;             // 1,792,000
    presplit_kernel<<<(chunks + 255) / 256, 256, 0, stream>>>(W, b, whi);
    (void)hipFuncSetAttribute(reinterpret_cast<const void*>(resnet_main<1>),
                              hipFuncAttributeMaxDynamicSharedMemorySize, SMEM_BYTES);
    resnet_main<1><<<nwg, 256, SMEM_BYTES, stream>>>(x, W, b, Wf, bf, out, whi);
  } else {
    (void)hipFuncSetAttribute(reinterpret_cast<const void*>(resnet_main<0>),
                              hipFuncAttributeMaxDynamicSharedMemorySize, SMEM_BYTES);
    resnet_main<0><<<nwg, 256, SMEM_BYTES, stream>>>(x, W, b, Wf, bf, out, nullptr);
  }
}

// Round 17
// 2086.703 us; speedup vs baseline: 1.1527x; 1.1527x over previous
//
#include <hip/hip_runtime.h>
#include <hip/hip_bf16.h>

#define N_LAYERS 1000
#define DD 100
#define DOUT 10
#define FRAG 4096                 // bytes per (layer,ks) fragment: 4 groups * 64 lanes * 16B
#define LSTRIDE (7 * FRAG)        // 28672 B per layer
#define POFF_MAX ((size_t)(N_LAYERS * 7 - 1) * FRAG)

typedef short s8v __attribute__((ext_vector_type(8)));
typedef float f16v __attribute__((ext_vector_type(16)));
typedef float f4v __attribute__((ext_vector_type(4)));

__device__ __forceinline__ unsigned short f2bf(float f) {
  __hip_bfloat16 h = __float2bfloat16(f);   // HW RNE
  return *reinterpret_cast<unsigned short*>(&h);
}
__device__ __forceinline__ float bf2f(unsigned short h) {
  return __uint_as_float(((unsigned)h) << 16);
}
__device__ __forceinline__ unsigned pk2(float a, float b) {  // packed bf16 pair (RNE)
  return (unsigned)f2bf(a) | ((unsigned)f2bf(b) << 16);
}

// ---------------- prologue: W (f32) + bias -> lane-packed bf16 fragments, ks-contiguous ----
// byte off = (L*7+ks)*4096 + gf*1024 + lane*16
// frag (gf,lane): n = gf*32+(lane&31), k = ks*16+(lane>>5)*8+j ; k==100 holds bias; pads 0.
__global__ __launch_bounds__(256)
void presplit_kernel(const float* __restrict__ W, const float* __restrict__ b,
                     char* __restrict__ hi_g) {
  int idx = blockIdx.x * 256 + threadIdx.x;
  if (idx >= N_LAYERS * 7 * 4 * 64) return;
  int lane = idx & 63;
  int gf = (idx >> 6) & 3;
  int r = idx >> 8;          // L*7 + ks
  int ks = r % 7;
  int L = r / 7;
  int n = gf * 32 + (lane & 31);
  int k0 = ks * 16 + (lane >> 5) * 8;
  s8v hv;
#pragma unroll
  for (int j = 0; j < 8; ++j) {
    int k = k0 + j;
    float v = 0.0f;
    if (n < DD) {
      if (k < DD) v = W[((size_t)L * DD + n) * DD + k];
      else if (k == DD) v = b[(size_t)L * DD + n];
    }
    hv[j] = (short)f2bf(v);
  }
  *(s8v*)(hi_g + (size_t)idx * 16) = hv;
}

// fallback W gather from raw f32 (all 4 groups of one ks; used when d_ws too small)
__device__ __forceinline__ void wload_f32(s8v* h, int L, int ks, int l31, int lhi,
                                          const float* __restrict__ W_g,
                                          const float* __restrict__ b_g) {
#pragma unroll
  for (int gf = 0; gf < 4; ++gf) {
    int n = gf * 32 + l31;
    int k0 = ks * 16 + lhi * 8;
    s8v hv;
#pragma unroll
    for (int j = 0; j < 8; ++j) {
      int k = k0 + j;
      float v = 0.0f;
      if (n < DD) {
        if (k < DD) v = W_g[((size_t)L * DD + n) * DD + k];
        else if (k == DD) v = b_g[(size_t)L * DD + n];
      }
      hv[j] = (short)f2bf(v);
    }
    h[gf] = hv;
  }
}

// ---------------- one layer, phase LP of 4 (depth-4 W slots, fully in-register act) --------
// Fragment stream t = 7L+ks in slot t&3 = (3*LP+ks)&3. poff advances uniformly +FRAG
// (ks-contiguous pack -> no layer-boundary special case).
// Epilogue: relu(+xr from LDS at block end) -> cvt_pk quads -> 2 permlane32_swap per ks
// rebuild next layer's B-fragments entirely in registers. No barriers.
template <int PRE, int LP>
__device__ __forceinline__ void layer_step(
    int L, s8v (&bf)[7], s8v (&wh)[4][4],
    const char* __restrict__ pW, size_t& poff, char* __restrict__ xrb,
    const f16v& zro, const float* __restrict__ W_g, const float* __restrict__ b_g,
    int l31, int lhi) {
  const bool bend = ((L % 10) == 9);
  f16v acc[4];
#pragma unroll
  for (int ks = 0; ks < 7; ++ks) {
    const int s = (3 * LP + ks) & 3;
    if (ks == 0) {
#pragma unroll
      for (int g = 0; g < 4; ++g)
        acc[g] = __builtin_amdgcn_mfma_f32_32x32x16_bf16(wh[s][g], bf[0], zro, 0, 0, 0);
    } else {
#pragma unroll
      for (int g = 0; g < 4; ++g)
        acc[g] = __builtin_amdgcn_mfma_f32_32x32x16_bf16(wh[s][g], bf[ks], acc[g], 0, 0, 0);
    }
    // refill slot s with fragment t+4 (uniform offset walk)
    if (PRE) {
      if (poff <= POFF_MAX) {
#pragma unroll
        for (int g = 0; g < 4; ++g)
          wh[s][g] = *(const s8v*)(pW + poff + g * 1024);
      }
      poff += FRAG;
    } else {
      const int Ln = L + (ks >= 3 ? 1 : 0);
      const int nks = (ks + 4) % 7;
      if (Ln < N_LAYERS) wload_f32(wh[s], Ln, nks, l31, lhi, W_g, b_g);
    }
  }

  // ---- epilogue: relu (+residual), pack, lane-swap rebuild of B-fragments ----
  unsigned P0[4][4], P1[4][4];
#pragma unroll
  for (int g = 0; g < 4; ++g) {
#pragma unroll
    for (int q = 0; q < 4; ++q) {
      float o0 = fmaxf(acc[g][4 * q + 0], 0.0f);
      float o1 = fmaxf(acc[g][4 * q + 1], 0.0f);
      float o2 = fmaxf(acc[g][4 * q + 2], 0.0f);
      float o3 = fmaxf(acc[g][4 * q + 3], 0.0f);
      if (bend) {   // thread-private LDS slots, no sync needed
        f4v xq = *(const f4v*)(xrb + (g * 4 + q) * 2048);
        o0 += xq[0]; o1 += xq[1]; o2 += xq[2]; o3 += xq[3];
        f4v nv; nv[0] = o0; nv[1] = o1; nv[2] = o2; nv[3] = o3;
        *(f4v*)(xrb + (g * 4 + q) * 2048) = nv;
      }
      P0[g][q] = pk2(o0, o1);
      P1[g][q] = pk2(o2, o3);
    }
  }
  // B-frag[ks] = channels [16ks+8lhi, +8): quads (g=ks>>1, qa=2(ks&1)) own + partner halves.
  // swap(D,S): lane<32 -> (ownD, partnerD); lane>=32 -> (partnerS, ownS) => uniform word map.
#pragma unroll
  for (int ks = 0; ks < 7; ++ks) {
    const int g = ks >> 1;
    const int qa = 2 * (ks & 1);
    auto rA = __builtin_amdgcn_permlane32_swap((int)P0[g][qa], (int)P0[g][qa + 1], false, false);
    auto rB = __builtin_amdgcn_permlane32_swap((int)P1[g][qa], (int)P1[g][qa + 1], false, false);
    union { s8v v; unsigned u[4]; } t;
    t.u[0] = (unsigned)rA[0];
    t.u[1] = (unsigned)rB[0];
    t.u[2] = (ks == 6) ? 0x3F80u : (unsigned)rA[1];   // bias column act[100]=1.0 (dead for lhi=1)
    t.u[3] = (unsigned)rB[1];
    bf[ks] = t.v;
  }
}

// ---------------- main kernel: 1024 wgs x 128 thr (2 waves), 4 wgs/CU, ZERO barriers -------
// Wave owns 32 batch rows x all 128 padded channels. Act never touches LDS; residual xr in
// thread-private LDS slots. W streamed from packed global, depth-4 register pipeline.
template <int PRE>
__global__ __launch_bounds__(128, 2)
void resnet_main(const float* __restrict__ x_g,
                 const float* __restrict__ W_g, const float* __restrict__ b_g,
                 const float* __restrict__ Wf_g, const float* __restrict__ bf_g,
                 float* __restrict__ out_g,
                 const char* __restrict__ whi_g) {
  __shared__ char xs[32768];   // xr: 16 blocks x 128 threads x 16B; reused for Wf at the end

  const int tid = threadIdx.x;
  const int lane = tid & 63;
  const int wv = tid >> 6;
  const int l31 = lane & 31;
  const int lhi = lane >> 5;
  const int row = blockIdx.x * 64 + wv * 32 + l31;   // this thread's batch row

  // ---- initial B-fragments straight from x (bf16, bias col 1.0, pads 0) ----
  s8v bf[7];
#pragma unroll
  for (int ks = 0; ks < 7; ++ks) {
    const int k0 = ks * 16 + lhi * 8;
    unsigned w[4];
#pragma unroll
    for (int p = 0; p < 4; ++p) {
      const int ka = k0 + 2 * p, kb = k0 + 2 * p + 1;
      float a0 = (ka < DD) ? x_g[(size_t)row * DD + ka] : (ka == DD ? 1.0f : 0.0f);
      float a1 = (kb < DD) ? x_g[(size_t)row * DD + kb] : (kb == DD ? 1.0f : 0.0f);
      w[p] = pk2(a0, a1);
    }
    union { s8v v; unsigned u[4]; } t;
    t.u[0] = w[0]; t.u[1] = w[1]; t.u[2] = w[2]; t.u[3] = w[3];
    bf[ks] = t.v;
  }

  // ---- residual xr -> thread-private LDS slots (C-fragment layout) ----
  char* xrb = xs + tid * 16;
#pragma unroll
  for (int g = 0; g < 4; ++g) {
#pragma unroll
    for (int q = 0; q < 4; ++q) {
      f4v xq;
#pragma unroll
      for (int j = 0; j < 4; ++j) {
        int c = 32 * g + 8 * q + j + 4 * lhi;
        xq[j] = (c < DD) ? x_g[(size_t)row * DD + c] : 0.0f;
      }
      *(f4v*)(xrb + (g * 4 + q) * 2048) = xq;
    }
  }

  f16v zro;
#pragma unroll
  for (int r = 0; r < 16; ++r) zro[r] = 0.0f;

  // ---- depth-4 W pipeline: preload fragments t=0..3 ----
  const char* pW = whi_g + lane * 16;
  s8v wh[4][4];
  if (PRE) {
#pragma unroll
    for (int s = 0; s < 4; ++s)
#pragma unroll
      for (int g = 0; g < 4; ++g)
        wh[s][g] = *(const s8v*)(pW + s * FRAG + g * 1024);
  } else {
#pragma unroll
    for (int s = 0; s < 4; ++s) wload_f32(wh[s], 0, s, l31, lhi, W_g, b_g);
  }
  size_t poff = 4 * FRAG;

  // ---- 1000 layers, no barriers ----
  for (int L = 0; L < N_LAYERS; L += 4) {
    layer_step<PRE, 0>(L + 0, bf, wh, pW, poff, xrb, zro, W_g, b_g, l31, lhi);
    layer_step<PRE, 1>(L + 1, bf, wh, pW, poff, xrb, zro, W_g, b_g, l31, lhi);
    layer_step<PRE, 2>(L + 2, bf, wh, pW, poff, xrb, zro, W_g, b_g, l31, lhi);
    layer_step<PRE, 3>(L + 3, bf, wh, pW, poff, xrb, zro, W_g, b_g, l31, lhi);
  }

  // ---- final projection: out = act @ Wf^T + bf ----
  __syncthreads();                       // xr dead; reuse xs for Wf broadcast
  float* xsf = (float*)xs;
  for (int i = tid; i < DOUT * DD; i += 128) xsf[i] = Wf_g[i];
  __syncthreads();

  float part[DOUT];
#pragma unroll
  for (int o = 0; o < DOUT; ++o) part[o] = 0.0f;
#pragma unroll
  for (int ks = 0; ks < 7; ++ks) {
#pragma unroll
    for (int j = 0; j < 8; ++j) {
      const int k = ks * 16 + lhi * 8 + j;
      if (k < DD) {
        float a = bf2f((unsigned short)bf[ks][j]);
#pragma unroll
        for (int o = 0; o < DOUT; ++o) part[o] += a * xsf[o * DD + k];
      }
    }
  }
#pragma unroll
  for (int o = 0; o < DOUT; ++o) part[o] += __shfl_xor(part[o], 32);
  if (lhi == 0) {
#pragma unroll
    for (int o = 0; o < DOUT; ++o)
      out_g[(size_t)row * DOUT + o] = part[o] + bf_g[o];
  }
}

extern "C" void kernel_launch(void* const* d_in, const int* in_sizes, int n_in,
                              void* d_out, int out_size, void* d_ws, size_t ws_size,
                              hipStream_t stream) {
  const float* x = (const float*)d_in[0];
  const float* W = (const float*)d_in[1];
  const float* b = (const float*)d_in[2];
  const float* Wf = (const float*)d_in[3];
  const float* bf = (const float*)d_in[4];
  float* out = (float*)d_out;

  const size_t need = (size_t)N_LAYERS * LSTRIDE;             // 28.672 MB
  const int nwg = 65536 / 64;                                 // 1024
  if (ws_size >= need) {
    char* whi = (char*)d_ws;
    const int chunks = N_LAYERS * 7 * 4 * 64;                 // 1,792,000
    presplit_kernel<<<(chunks + 255) / 256, 256, 0, stream>>>(W, b, whi);
    resnet_main<1><<<nwg, 128, 0, stream>>>(x, W, b, Wf, bf, out, whi);
  } else {
    resnet_main<0><<<nwg, 128, 0, stream>>>(x, W, b, Wf, bf, out, nullptr);
  }
}